// Round 5
// baseline (568.831 us; speedup 1.0000x reference)
//
#include <hip/hip_runtime.h>
#include <cstdint>
#include <cstddef>

typedef __attribute__((ext_vector_type(4))) float f32x4;
typedef __attribute__((ext_vector_type(8))) short bf16x8;      // MFMA operand (8 bf16)
typedef __attribute__((ext_vector_type(8))) unsigned short u16x8;
typedef __attribute__((ext_vector_type(4))) float float4v;
typedef __attribute__((ext_vector_type(2))) unsigned long long u64x2;
typedef unsigned long long ull;

// ---- problem dims ----
#define NB   8
#define TIN  200
#define TO1  51
#define VSZ  1024
#define HSZ  512
static constexpr int MJOINT = NB * TIN * TO1;   // 81600
static constexpr int MROWS  = TO1 * NB;         // 408  (rows t*8+n)

// ---- ws layout (bytes) ----
static constexpr size_t B_ENCBF = 0;                           // 1664*512*2
static constexpr size_t B_ENCW  = B_ENCBF + 1664ull*512*2;     // 512*512*2
static constexpr size_t B_DECW  = B_ENCW  + 512ull*512*2;
static constexpr size_t B_OUTW  = B_DECW  + 512ull*512*2;      // 1024*512*2
static constexpr size_t B_WIH   = B_OUTW  + 1024ull*512*2;     // 3*2048*512*2
static constexpr size_t B_WHH   = B_WIH   + 3ull*2048*512*2;
static constexpr size_t B_XTR   = B_WHH   + 3ull*2048*512*2;   // 4*408*512*2 (x0,h1,h2,h3 traces)
static constexpr size_t B_BSUM  = B_XTR   + 4ull*408*512*2;    // 3*2048*4
static constexpr size_t B_FLAGS = B_BSUM  + 3ull*2048*4;       // 96 flags x 64B = 6144 (pad 8192)
static constexpr size_t B_ENCP  = B_FLAGS + 8192;              // 1664*512*4
static constexpr size_t B_DECP  = B_ENCP  + 1664ull*512*4;     // 512*512*4
static constexpr size_t B_ABUF  = B_DECP  + 512ull*512*4;      // 81664*512*2

// ---- helpers ----
__device__ __forceinline__ unsigned short f2bf(float f) {
  union { float f; unsigned u; } v; v.f = f;
  unsigned r = v.u + 0x7FFFu + ((v.u >> 16) & 1u);
  return (unsigned short)(r >> 16);
}
__device__ __forceinline__ float fast_tanh(float x) {
  float t = __expf(2.0f * x);          // inf-safe: x>>0 -> 1, x<<0 -> -1
  return 1.0f - 2.0f / (t + 1.0f);
}
__device__ __forceinline__ float fast_sig(float x) {
  return 1.0f / (1.0f + __expf(-x));
}
__device__ __forceinline__ void gll16(const void* g, void* l) {
  __builtin_amdgcn_global_load_lds(
      (const __attribute__((address_space(1))) unsigned int*)g,
      (__attribute__((address_space(3))) unsigned int*)l, 16, 0, 0);
}
__device__ __forceinline__ void cvt8(const float* s, unsigned short* d) {
  const float4v* sp = (const float4v*)s;
  float4v x = sp[0], y = sp[1];
  u16x8 o;
  o[0]=f2bf(x[0]); o[1]=f2bf(x[1]); o[2]=f2bf(x[2]); o[3]=f2bf(x[3]);
  o[4]=f2bf(y[0]); o[5]=f2bf(y[1]); o[6]=f2bf(y[2]); o[7]=f2bf(y[3]);
  *(u16x8*)d = o;
}

// ---------------- fused fp32 -> bf16 convert for all weight/activation tensors ----------------
static constexpr int N_ENC  = 102400;           // 8*200*512/8
static constexpr int N_ENCW = 32768;
static constexpr int N_DECW = 32768;
static constexpr int N_OUTW = 65536;
static constexpr int N_WIH  = 393216;
static constexpr int P0 = N_ENC, P1 = P0+N_ENCW, P2 = P1+N_DECW, P3 = P2+N_OUTW,
                     P4 = P3+N_WIH;   // total 1019904 (=3984*256)

__global__ __launch_bounds__(256) void cvt_all(const float* __restrict__ enc,
                                               const float* __restrict__ encw,
                                               const float* __restrict__ decw,
                                               const float* __restrict__ outw,
                                               const float* __restrict__ wih,
                                               const float* __restrict__ whh,
                                               unsigned short* __restrict__ d_enc,
                                               unsigned short* __restrict__ d_encw,
                                               unsigned short* __restrict__ d_decw,
                                               unsigned short* __restrict__ d_outw,
                                               unsigned short* __restrict__ d_wih,
                                               unsigned short* __restrict__ d_whh) {
  int i = blockIdx.x * 256 + threadIdx.x;
  const float* s; unsigned short* d; int rel;
  if      (i < P0) { s = enc;  d = d_enc;  rel = i; }
  else if (i < P1) { s = encw; d = d_encw; rel = i - P0; }
  else if (i < P2) { s = decw; d = d_decw; rel = i - P1; }
  else if (i < P3) { s = outw; d = d_outw; rel = i - P2; }
  else if (i < P4) { s = wih;  d = d_wih;  rel = i - P3; }
  else             { s = whh;  d = d_whh;  rel = i - P4; }
  cvt8(s + (size_t)rel * 8, d + (size_t)rel * 8);
}

// ---------------- bias sum: bsum = b_ih + b_hh ----------------
__global__ __launch_bounds__(256) void bsum_kernel(const float* __restrict__ a,
                                                   const float* __restrict__ b,
                                                   float* __restrict__ o, int n) {
  int i = blockIdx.x * 256 + threadIdx.x;
  if (i < n) o[i] = a[i] + b[i];
}

// ---------------- embedding gather -> bf16 xtr[0][t*8+n][512] ----------------
__global__ __launch_bounds__(256) void embed_kernel(const float* __restrict__ emb,
                                                    const int* __restrict__ tgt,
                                                    unsigned short* __restrict__ x0) {
  int idx = blockIdx.x * 256 + threadIdx.x;   // 408*64
  if (idx >= MROWS * 64) return;
  int m = idx >> 6, kc = (idx & 63) * 8;
  int t = m >> 3, n = m & 7;
  int v = tgt[n * TO1 + t];
  cvt8(emb + (size_t)v * 512 + kc, x0 + (size_t)m * 512 + kc);
}

// ---------------- generic bf16 GEMM: C[M][N] = A[M][K] @ B[N][K]^T (+bias) ----------------
// 128x128 tile, BK=64, chunk-major LDS (conflict-free ds_read_b128 with linear gll16 dest),
// double-buffered 2-phase pipeline: STAGE(t+1) issued before compute(t), raw s_barrier +
// counted vmcnt(8) so prefetch loads stay in flight across the barrier (T3/T4 minimum).
__global__ __launch_bounds__(256) void gemm_bf16(const unsigned short* __restrict__ A,
                                                 const unsigned short* __restrict__ B,
                                                 float* __restrict__ C,
                                                 const float* __restrict__ bias,
                                                 int M, int N, int K) {
  // [buf][A=0/B=1][chunk-major tile]: elem (c*128+row)*8+e  (c = k/8 within BK=64)
  __shared__ __align__(16) unsigned short lds[2][2][8192];   // 64 KB
  const int tid = threadIdx.x;
  const int wave = tid >> 6, lane = tid & 63;
  const int lr = lane & 15, lg = lane >> 4;
  const int wm = (wave >> 1) * 64, wn = (wave & 1) * 64;

  // bijective XCD-aware remap (m204 form)
  const int nwg = gridDim.x * gridDim.y;
  const int id = blockIdx.y * gridDim.x + blockIdx.x;
  const int q = nwg >> 3, r = nwg & 7, xcd = id & 7, rest = id >> 3;
  const int nid = (xcd < r ? xcd * (q + 1) : r * (q + 1) + (xcd - r) * q) + rest;
  const size_t n0 = (size_t)(nid % gridDim.x) * 128;
  const size_t m0 = (size_t)(nid / gridDim.x) * 128;

  f32x4 acc[4][4];
#pragma unroll
  for (int i = 0; i < 4; ++i)
#pragma unroll
    for (int j = 0; j < 4; ++j) acc[i][j] = (f32x4){0.f, 0.f, 0.f, 0.f};

  // staging: unit u (0..3): idx8 = u*256+tid; chunk c = idx8>>7; row = idx8&127.
  // LDS dest (wave-uniform base): (u*256 + wave*64)*8 elems; lane offset is HW (+lane*16B).
#define STAGE(bf, kt)                                                                   \
  do {                                                                                  \
    _Pragma("unroll") for (int u = 0; u < 4; ++u) {                                     \
      const int idx8 = u * 256 + tid;                                                   \
      gll16(A + (m0 + (idx8 & 127)) * (size_t)K + (kt) + (idx8 >> 7) * 8,               \
            &lds[bf][0][(u * 256 + wave * 64) * 8]);                                    \
    }                                                                                   \
    _Pragma("unroll") for (int u = 0; u < 4; ++u) {                                     \
      const int idx8 = u * 256 + tid;                                                   \
      gll16(B + (n0 + (idx8 & 127)) * (size_t)K + (kt) + (idx8 >> 7) * 8,               \
            &lds[bf][1][(u * 256 + wave * 64) * 8]);                                    \
    }                                                                                   \
  } while (0)

  const int nt = K >> 6;
  int cur = 0;
  STAGE(0, 0);
  for (int t = 0; t < nt; ++t) {
    const int nxt = cur ^ 1;
    if (t + 1 < nt) {
      STAGE(nxt, (t + 1) * 64);
      asm volatile("s_waitcnt vmcnt(8)" ::: "memory");   // cur's 8 loads arrived; next 8 fly
    } else {
      asm volatile("s_waitcnt vmcnt(0)" ::: "memory");
    }
    __builtin_amdgcn_s_barrier();                        // all waves: buf[cur] fully staged
    const unsigned short* As_ = lds[cur][0];
    const unsigned short* Bs_ = lds[cur][1];
    __builtin_amdgcn_s_setprio(1);
#pragma unroll
    for (int half = 0; half < 2; ++half) {
      const int cb = half * 4 + lg;                      // this lane's k-chunk
      bf16x8 a[4], b[4];
#pragma unroll
      for (int i = 0; i < 4; ++i) a[i] = *(const bf16x8*)&As_[(cb * 128 + wm + i * 16 + lr) * 8];
#pragma unroll
      for (int j = 0; j < 4; ++j) b[j] = *(const bf16x8*)&Bs_[(cb * 128 + wn + j * 16 + lr) * 8];
#pragma unroll
      for (int i = 0; i < 4; ++i)
#pragma unroll
        for (int j = 0; j < 4; ++j)
          acc[i][j] = __builtin_amdgcn_mfma_f32_16x16x32_bf16(a[i], b[j], acc[i][j], 0, 0, 0);
    }
    __builtin_amdgcn_s_setprio(0);
    __builtin_amdgcn_s_barrier();                        // buf[cur] reads done -> reusable
    cur = nxt;
  }
#undef STAGE

  const int rq = lg * 4;
#pragma unroll
  for (int j = 0; j < 4; ++j) {
    const int col = (int)n0 + wn + j * 16 + lr;
    const float bv = bias ? bias[col] : 0.0f;
#pragma unroll
    for (int i = 0; i < 4; ++i) {
#pragma unroll
      for (int q2 = 0; q2 < 4; ++q2) {
        const long m = (long)m0 + wm + i * 16 + rq + q2;
        if (m < M) C[(size_t)m * N + col] = acc[i][j][q2] + bv;
      }
    }
  }
}

// ---------------- fused 3-layer LSTM: fence-free fine-grained pipeline ----------------
// 96 blocks x 256 thr: layer l = blk/32; block owns 16 hidden units (hid0=(blk%32)*16).
// Weights [wih|whh] (64 gate rows x K=1024, bf16) live in LDS (128KB), loaded once.
// ALL cross-block traffic (h rows, flags) is relaxed agent-scope atomics (write-through,
// coherence-point served) -> ZERO cache-maintenance ops in the step loop.
__global__ __launch_bounds__(256) void rnn_kernel(const unsigned short* __restrict__ wih,
                                                  const unsigned short* __restrict__ whh,
                                                  const float* __restrict__ bsum,
                                                  unsigned short* __restrict__ xtr,
                                                  int* __restrict__ flags) {
  __shared__ __align__(16) unsigned short w_s[64 * 1024];   // 128 KB
  __shared__ __align__(16) unsigned short xh_s[8 * 1024];   // 16 KB  [row n][x(512)|h(512)]
  __shared__ float gates_s[4][8][16];

  const int tid = threadIdx.x;
  const int l = blockIdx.x >> 5;
  const int b32 = blockIdx.x & 31;
  const int hid0 = b32 << 4;
  const int wave = tid >> 6, lane = tid & 63;
  const int lr = lane & 15, lg = lane >> 4;   // fragment row (0..15), k-subgroup (0..3)
  const int r7 = lr & 7;

  // ---- load weight slice into LDS, XOR-swizzled (chunk c of 16B at c^(row&7)) ----
  {
    const int rl = tid >> 2;           // local row 0..63 (= gate*16 + unit)
    const int qt = tid & 3;            // quarter of the row
    const size_t R = (size_t)l * 2048 + (size_t)(rl >> 4) * 512 + hid0 + (rl & 15);
    const unsigned short* s0 = wih + R * 512;
    const unsigned short* s1 = whh + R * 512;
#pragma unroll
    for (int i = 0; i < 32; ++i) {
      int c = qt * 32 + i;
      bf16x8 wv = (c < 64) ? *(const bf16x8*)&s0[c * 8] : *(const bf16x8*)&s1[(c - 64) * 8];
      *(bf16x8*)&w_s[rl * 1024 + ((c ^ (rl & 7)) << 3)] = wv;
    }
  }
  const float bias = bsum[(size_t)l * 2048 + (size_t)wave * 512 + hid0 + lr];

  const unsigned short* xin = xtr + (size_t)l * MROWS * 512;
  unsigned short* xout = xtr + (size_t)(l + 1) * MROWS * 512;
  float c_reg = 0.f;                   // cell state (tid<128: n=tid>>4, j=tid&15)
  const int sr = tid >> 5;             // staging row 0..7
  const int sseg = tid & 31;           // staging 64B segment within 2KB row
  __syncthreads();

  for (int t = 0; t < TO1; ++t) {
    // ---- poll dependencies (wave0 only; no fences -- flags are coherent atomics) ----
    if (wave == 0) {
      const bool mine = lane < 32;
      const bool active = mine ? (t > 0) : (l > 0);
      const int fi = mine ? (l * 32 + lane) * 16 : ((l - 1) * 32 + (lane - 32)) * 16;
      const int need = mine ? t : t + 1;
      for (;;) {
        bool ok = true;
        if (active)
          ok = __hip_atomic_load(&flags[fi], __ATOMIC_RELAXED, __HIP_MEMORY_SCOPE_AGENT) >= need;
        if (__all(ok)) break;
        __builtin_amdgcn_s_sleep(1);
      }
    }
    __syncthreads();   // also protects xh_s reuse (prior compute finished)

    // ---- stage x(512)+h(512) rows via coherent atomic loads -> swizzled LDS ----
    {
      ull v[8];
      if (sseg < 16) {
        const ull* p = (const ull*)(xin + ((size_t)t * 8 + sr) * 512) + sseg * 8;
#pragma unroll
        for (int i = 0; i < 8; ++i)
          v[i] = __hip_atomic_load(p + i, __ATOMIC_RELAXED, __HIP_MEMORY_SCOPE_AGENT);
      } else if (t == 0) {
#pragma unroll
        for (int i = 0; i < 8; ++i) v[i] = 0ull;
      } else {
        const ull* p = (const ull*)(xout + ((size_t)(t - 1) * 8 + sr) * 512) + (sseg - 16) * 8;
#pragma unroll
        for (int i = 0; i < 8; ++i)
          v[i] = __hip_atomic_load(p + i, __ATOMIC_RELAXED, __HIP_MEMORY_SCOPE_AGENT);
      }
#pragma unroll
      for (int i2 = 0; i2 < 4; ++i2) {
        int c = sseg * 4 + i2;
        *(u64x2*)&xh_s[sr * 1024 + ((c ^ sr) << 3)] = (u64x2){v[2 * i2], v[2 * i2 + 1]};
      }
    }
    __syncthreads();

    // ---- 32 MFMAs per wave: gates[wave] for 16 units, batch 8 (rows 8..15 pad) ----
    {
      f32x4 acc0 = (f32x4){0.f, 0.f, 0.f, 0.f};
      f32x4 acc1 = (f32x4){0.f, 0.f, 0.f, 0.f};
      const int rw = wave * 16 + lr;
#pragma unroll
      for (int c32 = 0; c32 < 32; ++c32) {
        const int cc = c32 * 4 + lg;
        bf16x8 av = *(const bf16x8*)&xh_s[r7 * 1024 + ((cc ^ r7) << 3)];
        bf16x8 bv = *(const bf16x8*)&w_s[rw * 1024 + ((cc ^ r7) << 3)];
        if (c32 & 1) acc1 = __builtin_amdgcn_mfma_f32_16x16x32_bf16(av, bv, acc1, 0, 0, 0);
        else         acc0 = __builtin_amdgcn_mfma_f32_16x16x32_bf16(av, bv, acc0, 0, 0, 0);
      }
      f32x4 g = acc0 + acc1;
      const int nb4 = lg * 4;
#pragma unroll
      for (int q2 = 0; q2 < 4; ++q2) {
        int n = nb4 + q2;
        if (n < 8) gates_s[wave][n][lr] = g[q2] + bias;
      }
    }
    __syncthreads();

    // ---- nonlinearity + coherent h store (atomic write-through) ----
    if (tid < 128) {
      const int n = tid >> 4, j = tid & 15;
      float gi = gates_s[0][n][j], gf = gates_s[1][n][j];
      float gg = gates_s[2][n][j], go = gates_s[3][n][j];
      c_reg = fast_sig(gf) * c_reg + fast_sig(gi) * fast_tanh(gg);
      float ht = fast_sig(go) * fast_tanh(c_reg);
      float htn = __shfl_down(ht, 1);
      if (!(j & 1)) {
        unsigned pk = (unsigned)f2bf(ht) | ((unsigned)f2bf(htn) << 16);
        unsigned* dst = (unsigned*)(xout + ((size_t)t * 8 + n) * 512 + hid0 + j);
        __hip_atomic_store(dst, pk, __ATOMIC_RELAXED, __HIP_MEMORY_SCOPE_AGENT);
      }
    }
    asm volatile("s_waitcnt vmcnt(0)" ::: "memory");   // h at coherence point
    __syncthreads();                                   // ...for ALL waves
    if (tid == 0)
      __hip_atomic_store(&flags[(l * 32 + b32) * 16], t + 1,
                         __ATOMIC_RELAXED, __HIP_MEMORY_SCOPE_AGENT);
  }
}

// ---------------- A = tanh(enc_p + dec_p) -> bf16 [81664][512] ----------------
__global__ __launch_bounds__(256) void tanha_kernel(const float* __restrict__ encp,
                                                    const float* __restrict__ decp,
                                                    unsigned short* __restrict__ Ab) {
  size_t idx = (size_t)blockIdx.x * 256 + threadIdx.x;
  int m = (int)(idx >> 6);
  int kc = ((int)idx & 63) * 8;
  if (m >= 81664) return;
  u16x8 o;
  if (m >= MJOINT) {
    o[0]=0;o[1]=0;o[2]=0;o[3]=0;o[4]=0;o[5]=0;o[6]=0;o[7]=0;
  } else {
    int n = m / (TIN * TO1);
    int rem = m - n * (TIN * TO1);
    int t = rem / TO1;
    int u = rem - t * TO1;
    const float4v* ep = (const float4v*)(encp + ((size_t)n * TIN + t) * 512 + kc);
    const float4v* dp = (const float4v*)(decp + ((size_t)u * 8 + n) * 512 + kc);
    float4v e0 = ep[0], e1 = ep[1], d0 = dp[0], d1 = dp[1];
    o[0]=f2bf(fast_tanh(e0[0]+d0[0])); o[1]=f2bf(fast_tanh(e0[1]+d0[1]));
    o[2]=f2bf(fast_tanh(e0[2]+d0[2])); o[3]=f2bf(fast_tanh(e0[3]+d0[3]));
    o[4]=f2bf(fast_tanh(e1[0]+d1[0])); o[5]=f2bf(fast_tanh(e1[1]+d1[1]));
    o[6]=f2bf(fast_tanh(e1[2]+d1[2])); o[7]=f2bf(fast_tanh(e1[3]+d1[3]));
  }
  *(u16x8*)(Ab + (size_t)m * 512 + kc) = o;
}

// ---------------- launch ----------------
extern "C" void kernel_launch(void* const* d_in, const int* in_sizes, int n_in,
                              void* d_out, int out_size, void* d_ws, size_t ws_size,
                              hipStream_t stream) {
  (void)in_sizes; (void)n_in; (void)out_size; (void)ws_size;
  const float* enc_out = (const float*)d_in[0];
  const int*   tgt     = (const int*)d_in[1];
  const float* embed   = (const float*)d_in[2];
  const float* w_ih    = (const float*)d_in[3];
  const float* w_hh    = (const float*)d_in[4];
  const float* b_ih    = (const float*)d_in[5];
  const float* b_hh    = (const float*)d_in[6];
  const float* enc_w   = (const float*)d_in[7];
  const float* dec_w   = (const float*)d_in[8];
  const float* dec_b   = (const float*)d_in[9];
  const float* out_w   = (const float*)d_in[10];

  char* ws = (char*)d_ws;
  unsigned short* enc_bf  = (unsigned short*)(ws + B_ENCBF);
  unsigned short* encw_bf = (unsigned short*)(ws + B_ENCW);
  unsigned short* decw_bf = (unsigned short*)(ws + B_DECW);
  unsigned short* outw_bf = (unsigned short*)(ws + B_OUTW);
  unsigned short* wih_bf  = (unsigned short*)(ws + B_WIH);
  unsigned short* whh_bf  = (unsigned short*)(ws + B_WHH);
  unsigned short* xtr     = (unsigned short*)(ws + B_XTR);
  float* bsum  = (float*)(ws + B_BSUM);
  int*   flags = (int*)(ws + B_FLAGS);
  float* encp  = (float*)(ws + B_ENCP);
  float* decp  = (float*)(ws + B_DECP);
  unsigned short* abuf = (unsigned short*)(ws + B_ABUF);
  float* Cout  = (float*)d_out;

  hipMemsetAsync(flags, 0, 6144, stream);

  cvt_all<<<3984, 256, 0, stream>>>(enc_out, enc_w, dec_w, out_w, w_ih, w_hh,
                                    enc_bf, encw_bf, decw_bf, outw_bf, wih_bf, whh_bf);
  bsum_kernel<<<24, 256, 0, stream>>>(b_ih, b_hh, bsum, 6144);
  embed_kernel<<<102, 256, 0, stream>>>(embed, tgt, xtr);

  rnn_kernel<<<96, 256, 0, stream>>>(wih_bf, whh_bf, bsum, xtr, flags);

  gemm_bf16<<<dim3(4, 13), 256, 0, stream>>>(enc_bf, encw_bf, encp, nullptr, NB * TIN, 512, 512);
  gemm_bf16<<<dim3(4, 4), 256, 0, stream>>>(xtr + 3ull * MROWS * 512, decw_bf, decp, dec_b,
                                            MROWS, 512, 512);
  tanha_kernel<<<20416, 256, 0, stream>>>(encp, decp, abuf);
  gemm_bf16<<<dim3(8, 638), 256, 0, stream>>>(abuf, outw_bf, Cout, nullptr, MJOINT, VSZ, 512);
}

// Round 6
// 521.311 us; speedup vs baseline: 1.0912x; 1.0912x over previous
//
#include <hip/hip_runtime.h>
#include <cstdint>
#include <cstddef>

typedef __attribute__((ext_vector_type(4))) float f32x4;
typedef __attribute__((ext_vector_type(8))) short bf16x8;      // MFMA operand (8 bf16)
typedef __attribute__((ext_vector_type(8))) unsigned short u16x8;
typedef __attribute__((ext_vector_type(4))) float float4v;
typedef __attribute__((ext_vector_type(2))) unsigned long long u64x2;
typedef unsigned long long ull;

// ---- problem dims ----
#define NB   8
#define TIN  200
#define TO1  51
#define VSZ  1024
#define HSZ  512
static constexpr int MJOINT = NB * TIN * TO1;   // 81600
static constexpr int MROWS  = TO1 * NB;         // 408  (rows t*8+n)

// ---- ws layout (bytes) ----
static constexpr size_t B_ENCBF = 0;                           // 1664*512*2
static constexpr size_t B_ENCW  = B_ENCBF + 1664ull*512*2;     // 512*512*2
static constexpr size_t B_DECW  = B_ENCW  + 512ull*512*2;
static constexpr size_t B_OUTW  = B_DECW  + 512ull*512*2;      // 1024*512*2
static constexpr size_t B_WIH   = B_OUTW  + 1024ull*512*2;     // 3*2048*512*2
static constexpr size_t B_WHH   = B_WIH   + 3ull*2048*512*2;
static constexpr size_t B_XTR   = B_WHH   + 3ull*2048*512*2;   // 4*408*512*2 (x0,h1,h2,h3 traces)
static constexpr size_t B_BSUM  = B_XTR   + 4ull*408*512*2;    // 3*2048*4
static constexpr size_t B_FLAGS = B_BSUM  + 3ull*2048*4;       // 96 flags x 64B = 6144 (pad 8192)
static constexpr size_t B_ENCP  = B_FLAGS + 8192;              // 1664*512*4
static constexpr size_t B_DECP  = B_ENCP  + 1664ull*512*4;     // 512*512*4
static constexpr size_t B_ABUF  = B_DECP  + 512ull*512*4;      // 81664*512*2

// ---- helpers ----
__device__ __forceinline__ unsigned short f2bf(float f) {
  union { float f; unsigned u; } v; v.f = f;
  unsigned r = v.u + 0x7FFFu + ((v.u >> 16) & 1u);
  return (unsigned short)(r >> 16);
}
__device__ __forceinline__ float fast_tanh(float x) {
  float t = __expf(2.0f * x);          // inf-safe: x>>0 -> 1, x<<0 -> -1
  return 1.0f - 2.0f / (t + 1.0f);
}
__device__ __forceinline__ float fast_sig(float x) {
  return 1.0f / (1.0f + __expf(-x));
}
__device__ __forceinline__ void gll16(const void* g, void* l) {
  __builtin_amdgcn_global_load_lds(
      (const __attribute__((address_space(1))) unsigned int*)g,
      (__attribute__((address_space(3))) unsigned int*)l, 16, 0, 0);
}
__device__ __forceinline__ void cvt8(const float* s, unsigned short* d) {
  const float4v* sp = (const float4v*)s;
  float4v x = sp[0], y = sp[1];
  u16x8 o;
  o[0]=f2bf(x[0]); o[1]=f2bf(x[1]); o[2]=f2bf(x[2]); o[3]=f2bf(x[3]);
  o[4]=f2bf(y[0]); o[5]=f2bf(y[1]); o[6]=f2bf(y[2]); o[7]=f2bf(y[3]);
  *(u16x8*)d = o;
}

// ---------------- fused fp32 -> bf16 convert for all weight/activation tensors ----------------
static constexpr int N_ENC  = 102400;           // 8*200*512/8
static constexpr int N_ENCW = 32768;
static constexpr int N_DECW = 32768;
static constexpr int N_OUTW = 65536;
static constexpr int N_WIH  = 393216;
static constexpr int P0 = N_ENC, P1 = P0+N_ENCW, P2 = P1+N_DECW, P3 = P2+N_OUTW,
                     P4 = P3+N_WIH;   // total 1019904 (=3984*256)

__global__ __launch_bounds__(256) void cvt_all(const float* __restrict__ enc,
                                               const float* __restrict__ encw,
                                               const float* __restrict__ decw,
                                               const float* __restrict__ outw,
                                               const float* __restrict__ wih,
                                               const float* __restrict__ whh,
                                               unsigned short* __restrict__ d_enc,
                                               unsigned short* __restrict__ d_encw,
                                               unsigned short* __restrict__ d_decw,
                                               unsigned short* __restrict__ d_outw,
                                               unsigned short* __restrict__ d_wih,
                                               unsigned short* __restrict__ d_whh) {
  int i = blockIdx.x * 256 + threadIdx.x;
  const float* s; unsigned short* d; int rel;
  if      (i < P0) { s = enc;  d = d_enc;  rel = i; }
  else if (i < P1) { s = encw; d = d_encw; rel = i - P0; }
  else if (i < P2) { s = decw; d = d_decw; rel = i - P1; }
  else if (i < P3) { s = outw; d = d_outw; rel = i - P2; }
  else if (i < P4) { s = wih;  d = d_wih;  rel = i - P3; }
  else             { s = whh;  d = d_whh;  rel = i - P4; }
  cvt8(s + (size_t)rel * 8, d + (size_t)rel * 8);
}

// ---------------- bias sum: bsum = b_ih + b_hh ----------------
__global__ __launch_bounds__(256) void bsum_kernel(const float* __restrict__ a,
                                                   const float* __restrict__ b,
                                                   float* __restrict__ o, int n) {
  int i = blockIdx.x * 256 + threadIdx.x;
  if (i < n) o[i] = a[i] + b[i];
}

// ---------------- embedding gather -> bf16 xtr[0][t*8+n][512] ----------------
__global__ __launch_bounds__(256) void embed_kernel(const float* __restrict__ emb,
                                                    const int* __restrict__ tgt,
                                                    unsigned short* __restrict__ x0) {
  int idx = blockIdx.x * 256 + threadIdx.x;   // 408*64
  if (idx >= MROWS * 64) return;
  int m = idx >> 6, kc = (idx & 63) * 8;
  int t = m >> 3, n = m & 7;
  int v = tgt[n * TO1 + t];
  cvt8(emb + (size_t)v * 512 + kc, x0 + (size_t)m * 512 + kc);
}

// ---------------- generic bf16 GEMM: C[M][N] = A[M][K] @ B[N][K]^T (+bias) ----------------
// 128x128 tile, BK=32. Row-major XOR-swizzled LDS: row r has 4 slots of 16B; slot cs holds
// global chunk cs ^ (r&3). Staged linearly by global_load_lds with PRE-SWIZZLED global source
// (coalesced 64B row segments); fragment ds_read_b128 spreads 8 balanced 4-bank groups -> ~0
// conflicts. Double-buffered, counted vmcnt(4): prefetch stays in flight across the barrier.
__global__ __launch_bounds__(256) void gemm_bf16(const unsigned short* __restrict__ A,
                                                 const unsigned short* __restrict__ B,
                                                 float* __restrict__ C,
                                                 const float* __restrict__ bias,
                                                 int M, int N, int K) {
  __shared__ __align__(16) unsigned short lds[2][2][4096];   // [buf][A/B][128*32] = 32 KB
  const int tid = threadIdx.x;
  const int wave = tid >> 6, lane = tid & 63;
  const int lr = lane & 15, lg = lane >> 4;
  const int wm = (wave >> 1) * 64, wn = (wave & 1) * 64;
  const int xsl = (lg ^ (lr & 3)) << 3;   // lane-constant swizzled fragment slot (elems)

  // bijective XCD-aware remap (m204 form)
  const int nwg = gridDim.x * gridDim.y;
  const int id = blockIdx.y * gridDim.x + blockIdx.x;
  const int q = nwg >> 3, r = nwg & 7, xcd = id & 7, rest = id >> 3;
  const int nid = (xcd < r ? xcd * (q + 1) : r * (q + 1) + (xcd - r) * q) + rest;
  const size_t n0 = (size_t)(nid % gridDim.x) * 128;
  const size_t m0 = (size_t)(nid / gridDim.x) * 128;

  f32x4 acc[4][4];
#pragma unroll
  for (int i = 0; i < 4; ++i)
#pragma unroll
    for (int j = 0; j < 4; ++j) acc[i][j] = (f32x4){0.f, 0.f, 0.f, 0.f};

  // staging: slot s = u*256+tid (u=0,1); row = s>>2; global chunk = (s&3) ^ (row&3).
  // Per wave instr: 16 rows x 64B permuted-contiguous segments (cacheline-aligned perm).
#define STAGE(bf, kt)                                                                 \
  do {                                                                                \
    _Pragma("unroll") for (int u = 0; u < 2; ++u) {                                   \
      const int s = u * 256 + tid;                                                    \
      const int row_ = s >> 2;                                                        \
      const int ch = (s & 3) ^ (row_ & 3);                                            \
      gll16(A + (m0 + row_) * (size_t)K + (kt) + ch * 8,                              \
            &lds[bf][0][(u * 256 + wave * 64) * 8]);                                  \
    }                                                                                 \
    _Pragma("unroll") for (int u = 0; u < 2; ++u) {                                   \
      const int s = u * 256 + tid;                                                    \
      const int row_ = s >> 2;                                                        \
      const int ch = (s & 3) ^ (row_ & 3);                                            \
      gll16(B + (n0 + row_) * (size_t)K + (kt) + ch * 8,                              \
            &lds[bf][1][(u * 256 + wave * 64) * 8]);                                  \
    }                                                                                 \
  } while (0)

  const int nt = K >> 5;
  int cur = 0;
  STAGE(0, 0);
  for (int t = 0; t < nt; ++t) {
    if (t + 1 < nt) {
      STAGE(cur ^ 1, (t + 1) * 32);
      asm volatile("s_waitcnt vmcnt(4)" ::: "memory");   // buf[cur]'s 4 done; next 4 in flight
    } else {
      asm volatile("s_waitcnt vmcnt(0)" ::: "memory");
    }
    __builtin_amdgcn_s_barrier();                        // buf[cur] staged for all waves
    const unsigned short* As_ = lds[cur][0];
    const unsigned short* Bs_ = lds[cur][1];
    bf16x8 a[4], b[4];
#pragma unroll
    for (int i = 0; i < 4; ++i) a[i] = *(const bf16x8*)&As_[(wm + i * 16 + lr) * 32 + xsl];
#pragma unroll
    for (int j = 0; j < 4; ++j) b[j] = *(const bf16x8*)&Bs_[(wn + j * 16 + lr) * 32 + xsl];
    __builtin_amdgcn_s_setprio(1);
#pragma unroll
    for (int i = 0; i < 4; ++i)
#pragma unroll
      for (int j = 0; j < 4; ++j)
        acc[i][j] = __builtin_amdgcn_mfma_f32_16x16x32_bf16(a[i], b[j], acc[i][j], 0, 0, 0);
    __builtin_amdgcn_s_setprio(0);
    __builtin_amdgcn_s_barrier();                        // reads of buf[cur] done -> reusable
    cur ^= 1;
  }
#undef STAGE

  const int rq = lg * 4;
#pragma unroll
  for (int j = 0; j < 4; ++j) {
    const int col = (int)n0 + wn + j * 16 + lr;
    const float bv = bias ? bias[col] : 0.0f;
#pragma unroll
    for (int i = 0; i < 4; ++i) {
#pragma unroll
      for (int q2 = 0; q2 < 4; ++q2) {
        const long m = (long)m0 + wm + i * 16 + rq + q2;
        if (m < M) C[(size_t)m * N + col] = acc[i][j][q2] + bv;
      }
    }
  }
}

// ---------------- fused 3-layer LSTM: fence-free fine-grained pipeline ----------------
// 96 blocks x 256 thr: layer l = blk/32; block owns 16 hidden units (hid0=(blk%32)*16).
// Weights [wih|whh] (64 gate rows x K=1024, bf16) live in LDS (128KB), loaded once.
// ALL cross-block traffic (h rows, flags) is relaxed agent-scope atomics (write-through,
// coherence-point served) -> ZERO cache-maintenance ops in the step loop.
__global__ __launch_bounds__(256) void rnn_kernel(const unsigned short* __restrict__ wih,
                                                  const unsigned short* __restrict__ whh,
                                                  const float* __restrict__ bsum,
                                                  unsigned short* __restrict__ xtr,
                                                  int* __restrict__ flags) {
  __shared__ __align__(16) unsigned short w_s[64 * 1024];   // 128 KB
  __shared__ __align__(16) unsigned short xh_s[8 * 1024];   // 16 KB  [row n][x(512)|h(512)]
  __shared__ float gates_s[4][8][16];

  const int tid = threadIdx.x;
  const int l = blockIdx.x >> 5;
  const int b32 = blockIdx.x & 31;
  const int hid0 = b32 << 4;
  const int wave = tid >> 6, lane = tid & 63;
  const int lr = lane & 15, lg = lane >> 4;   // fragment row (0..15), k-subgroup (0..3)
  const int r7 = lr & 7;

  // ---- load weight slice into LDS, XOR-swizzled (chunk c of 16B at c^(row&7)) ----
  {
    const int rl = tid >> 2;           // local row 0..63 (= gate*16 + unit)
    const int qt = tid & 3;            // quarter of the row
    const size_t R = (size_t)l * 2048 + (size_t)(rl >> 4) * 512 + hid0 + (rl & 15);
    const unsigned short* s0 = wih + R * 512;
    const unsigned short* s1 = whh + R * 512;
#pragma unroll
    for (int i = 0; i < 32; ++i) {
      int c = qt * 32 + i;
      bf16x8 wv = (c < 64) ? *(const bf16x8*)&s0[c * 8] : *(const bf16x8*)&s1[(c - 64) * 8];
      *(bf16x8*)&w_s[rl * 1024 + ((c ^ (rl & 7)) << 3)] = wv;
    }
  }
  const float bias = bsum[(size_t)l * 2048 + (size_t)wave * 512 + hid0 + lr];

  const unsigned short* xin = xtr + (size_t)l * MROWS * 512;
  unsigned short* xout = xtr + (size_t)(l + 1) * MROWS * 512;
  float c_reg = 0.f;                   // cell state (tid<128: n=tid>>4, j=tid&15)
  const int sr = tid >> 5;             // staging row 0..7
  const int sseg = tid & 31;           // staging 64B segment within 2KB row
  __syncthreads();

  for (int t = 0; t < TO1; ++t) {
    // ---- poll dependencies (wave0 only; no fences -- flags are coherent atomics) ----
    if (wave == 0) {
      const bool mine = lane < 32;
      const bool active = mine ? (t > 0) : (l > 0);
      const int fi = mine ? (l * 32 + lane) * 16 : ((l - 1) * 32 + (lane - 32)) * 16;
      const int need = mine ? t : t + 1;
      for (;;) {
        bool ok = true;
        if (active)
          ok = __hip_atomic_load(&flags[fi], __ATOMIC_RELAXED, __HIP_MEMORY_SCOPE_AGENT) >= need;
        if (__all(ok)) break;
        __builtin_amdgcn_s_sleep(1);
      }
    }
    __syncthreads();   // also protects xh_s reuse (prior compute finished)

    // ---- stage x(512)+h(512) rows via coherent atomic loads -> swizzled LDS ----
    {
      ull v[8];
      if (sseg < 16) {
        const ull* p = (const ull*)(xin + ((size_t)t * 8 + sr) * 512) + sseg * 8;
#pragma unroll
        for (int i = 0; i < 8; ++i)
          v[i] = __hip_atomic_load(p + i, __ATOMIC_RELAXED, __HIP_MEMORY_SCOPE_AGENT);
      } else if (t == 0) {
#pragma unroll
        for (int i = 0; i < 8; ++i) v[i] = 0ull;
      } else {
        const ull* p = (const ull*)(xout + ((size_t)(t - 1) * 8 + sr) * 512) + (sseg - 16) * 8;
#pragma unroll
        for (int i = 0; i < 8; ++i)
          v[i] = __hip_atomic_load(p + i, __ATOMIC_RELAXED, __HIP_MEMORY_SCOPE_AGENT);
      }
#pragma unroll
      for (int i2 = 0; i2 < 4; ++i2) {
        int c = sseg * 4 + i2;
        *(u64x2*)&xh_s[sr * 1024 + ((c ^ sr) << 3)] = (u64x2){v[2 * i2], v[2 * i2 + 1]};
      }
    }
    __syncthreads();

    // ---- 32 MFMAs per wave: gates[wave] for 16 units, batch 8 (rows 8..15 pad) ----
    {
      f32x4 acc0 = (f32x4){0.f, 0.f, 0.f, 0.f};
      f32x4 acc1 = (f32x4){0.f, 0.f, 0.f, 0.f};
      const int rw = wave * 16 + lr;
#pragma unroll
      for (int c32 = 0; c32 < 32; ++c32) {
        const int cc = c32 * 4 + lg;
        bf16x8 av = *(const bf16x8*)&xh_s[r7 * 1024 + ((cc ^ r7) << 3)];
        bf16x8 bv = *(const bf16x8*)&w_s[rw * 1024 + ((cc ^ r7) << 3)];
        if (c32 & 1) acc1 = __builtin_amdgcn_mfma_f32_16x16x32_bf16(av, bv, acc1, 0, 0, 0);
        else         acc0 = __builtin_amdgcn_mfma_f32_16x16x32_bf16(av, bv, acc0, 0, 0, 0);
      }
      f32x4 g = acc0 + acc1;
      const int nb4 = lg * 4;
#pragma unroll
      for (int q2 = 0; q2 < 4; ++q2) {
        int n = nb4 + q2;
        if (n < 8) gates_s[wave][n][lr] = g[q2] + bias;
      }
    }
    __syncthreads();

    // ---- nonlinearity + coherent h store (atomic write-through) ----
    if (tid < 128) {
      const int n = tid >> 4, j = tid & 15;
      float gi = gates_s[0][n][j], gf = gates_s[1][n][j];
      float gg = gates_s[2][n][j], go = gates_s[3][n][j];
      c_reg = fast_sig(gf) * c_reg + fast_sig(gi) * fast_tanh(gg);
      float ht = fast_sig(go) * fast_tanh(c_reg);
      float htn = __shfl_down(ht, 1);
      if (!(j & 1)) {
        unsigned pk = (unsigned)f2bf(ht) | ((unsigned)f2bf(htn) << 16);
        unsigned* dst = (unsigned*)(xout + ((size_t)t * 8 + n) * 512 + hid0 + j);
        __hip_atomic_store(dst, pk, __ATOMIC_RELAXED, __HIP_MEMORY_SCOPE_AGENT);
      }
    }
    asm volatile("s_waitcnt vmcnt(0)" ::: "memory");   // h at coherence point
    __syncthreads();                                   // ...for ALL waves
    if (tid == 0)
      __hip_atomic_store(&flags[(l * 32 + b32) * 16], t + 1,
                         __ATOMIC_RELAXED, __HIP_MEMORY_SCOPE_AGENT);
  }
}

// ---------------- A = tanh(enc_p + dec_p) -> bf16 [81664][512] ----------------
__global__ __launch_bounds__(256) void tanha_kernel(const float* __restrict__ encp,
                                                    const float* __restrict__ decp,
                                                    unsigned short* __restrict__ Ab) {
  size_t idx = (size_t)blockIdx.x * 256 + threadIdx.x;
  int m = (int)(idx >> 6);
  int kc = ((int)idx & 63) * 8;
  if (m >= 81664) return;
  u16x8 o;
  if (m >= MJOINT) {
    o[0]=0;o[1]=0;o[2]=0;o[3]=0;o[4]=0;o[5]=0;o[6]=0;o[7]=0;
  } else {
    int n = m / (TIN * TO1);
    int rem = m - n * (TIN * TO1);
    int t = rem / TO1;
    int u = rem - t * TO1;
    const float4v* ep = (const float4v*)(encp + ((size_t)n * TIN + t) * 512 + kc);
    const float4v* dp = (const float4v*)(decp + ((size_t)u * 8 + n) * 512 + kc);
    float4v e0 = ep[0], e1 = ep[1], d0 = dp[0], d1 = dp[1];
    o[0]=f2bf(fast_tanh(e0[0]+d0[0])); o[1]=f2bf(fast_tanh(e0[1]+d0[1]));
    o[2]=f2bf(fast_tanh(e0[2]+d0[2])); o[3]=f2bf(fast_tanh(e0[3]+d0[3]));
    o[4]=f2bf(fast_tanh(e1[0]+d1[0])); o[5]=f2bf(fast_tanh(e1[1]+d1[1]));
    o[6]=f2bf(fast_tanh(e1[2]+d1[2])); o[7]=f2bf(fast_tanh(e1[3]+d1[3]));
  }
  *(u16x8*)(Ab + (size_t)m * 512 + kc) = o;
}

// ---------------- launch ----------------
extern "C" void kernel_launch(void* const* d_in, const int* in_sizes, int n_in,
                              void* d_out, int out_size, void* d_ws, size_t ws_size,
                              hipStream_t stream) {
  (void)in_sizes; (void)n_in; (void)out_size; (void)ws_size;
  const float* enc_out = (const float*)d_in[0];
  const int*   tgt     = (const int*)d_in[1];
  const float* embed   = (const float*)d_in[2];
  const float* w_ih    = (const float*)d_in[3];
  const float* w_hh    = (const float*)d_in[4];
  const float* b_ih    = (const float*)d_in[5];
  const float* b_hh    = (const float*)d_in[6];
  const float* enc_w   = (const float*)d_in[7];
  const float* dec_w   = (const float*)d_in[8];
  const float* dec_b   = (const float*)d_in[9];
  const float* out_w   = (const float*)d_in[10];

  char* ws = (char*)d_ws;
  unsigned short* enc_bf  = (unsigned short*)(ws + B_ENCBF);
  unsigned short* encw_bf = (unsigned short*)(ws + B_ENCW);
  unsigned short* decw_bf = (unsigned short*)(ws + B_DECW);
  unsigned short* outw_bf = (unsigned short*)(ws + B_OUTW);
  unsigned short* wih_bf  = (unsigned short*)(ws + B_WIH);
  unsigned short* whh_bf  = (unsigned short*)(ws + B_WHH);
  unsigned short* xtr     = (unsigned short*)(ws + B_XTR);
  float* bsum  = (float*)(ws + B_BSUM);
  int*   flags = (int*)(ws + B_FLAGS);
  float* encp  = (float*)(ws + B_ENCP);
  float* decp  = (float*)(ws + B_DECP);
  unsigned short* abuf = (unsigned short*)(ws + B_ABUF);
  float* Cout  = (float*)d_out;

  hipMemsetAsync(flags, 0, 6144, stream);

  cvt_all<<<3984, 256, 0, stream>>>(enc_out, enc_w, dec_w, out_w, w_ih, w_hh,
                                    enc_bf, encw_bf, decw_bf, outw_bf, wih_bf, whh_bf);
  bsum_kernel<<<24, 256, 0, stream>>>(b_ih, b_hh, bsum, 6144);
  embed_kernel<<<102, 256, 0, stream>>>(embed, tgt, xtr);

  rnn_kernel<<<96, 256, 0, stream>>>(wih_bf, whh_bf, bsum, xtr, flags);

  gemm_bf16<<<dim3(4, 13), 256, 0, stream>>>(enc_bf, encw_bf, encp, nullptr, NB * TIN, 512, 512);
  gemm_bf16<<<dim3(4, 4), 256, 0, stream>>>(xtr + 3ull * MROWS * 512, decw_bf, decp, dec_b,
                                            MROWS, 512, 512);
  tanha_kernel<<<20416, 256, 0, stream>>>(encp, decp, abuf);
  gemm_bf16<<<dim3(8, 638), 256, 0, stream>>>(abuf, outw_bf, Cout, nullptr, MJOINT, VSZ, 512);
}